// Round 1
// baseline (571.120 us; speedup 1.0000x reference)
//
#include <hip/hip_runtime.h>
#include <hip/hip_bf16.h>

// ---------------------------------------------------------------------------
// CrossLevelAttention on MI355X — round 1: correct fp32 baseline.
// B=2, H=W=256, N=65536. dim=256, dim_h=128, dim_l=64, HEADS=4.
// Pipeline:
//   1x1 convs (kv/qh/ql) -> pyramid dwconv (reflect pad, dil 1/2/3)
//   -> fused scores+sq-norms -> softmax+projection-fold (CT) -> out GEMM.
// ---------------------------------------------------------------------------

#define NPIX 65536  // 256*256 per batch image

// ---------------- zero small accumulator region ----------------
__global__ void zero_k(float* __restrict__ p, int n) {
    int i = blockIdx.x * 256 + threadIdx.x;
    if (i < n) p[i] = 0.f;
}

// ---------------- transpose 1x1 conv weights to [i][o] ----------------
__global__ void transpose_w_k(const float* __restrict__ w_kv,
                              const float* __restrict__ w_qh,
                              const float* __restrict__ w_ql,
                              float* __restrict__ wkvT,
                              float* __restrict__ wqhT,
                              float* __restrict__ wqlT) {
    int idx = blockIdx.x * 256 + threadIdx.x;
    if (idx < 32768) {                       // w_kv (128,256)
        int o = idx >> 8, i = idx & 255;
        wkvT[i * 128 + o] = w_kv[idx];
    } else if (idx < 32768 + 4096) {         // w_qh (32,128)
        int k = idx - 32768;
        int o = k >> 7, i = k & 127;
        wqhT[i * 32 + o] = w_qh[k];
    } else if (idx < 32768 + 4096 + 1024) {  // w_ql (16,64)
        int k = idx - 36864;
        int o = k >> 6, i = k & 63;
        wqlT[i * 16 + o] = w_ql[k];
    }
}

// ---------------- 1x1 conv: out[b,o,n] = sum_i wT[i][o] * x[b,i,n] ----------
template <int OC>
__global__ __launch_bounds__(256) void conv1x1_k(const float* __restrict__ x,
                                                 const float* __restrict__ wT,
                                                 float* __restrict__ out,
                                                 int I, int O) {
    const int t = threadIdx.x;
    const int n = blockIdx.x * 256 + t;
    const int oc0 = blockIdx.y * OC;
    const int b = blockIdx.z;

    const float* xp = x + (size_t)b * I * NPIX + n;
    float acc[OC];
#pragma unroll
    for (int o = 0; o < OC; ++o) acc[o] = 0.f;

#pragma unroll 2
    for (int i = 0; i < I; ++i) {
        float xv = xp[(size_t)i * NPIX];
        const float4* wr = (const float4*)(wT + (size_t)i * O + oc0);
#pragma unroll
        for (int o4 = 0; o4 < OC / 4; ++o4) {
            float4 wv = wr[o4];
            acc[o4 * 4 + 0] = fmaf(wv.x, xv, acc[o4 * 4 + 0]);
            acc[o4 * 4 + 1] = fmaf(wv.y, xv, acc[o4 * 4 + 1]);
            acc[o4 * 4 + 2] = fmaf(wv.z, xv, acc[o4 * 4 + 2]);
            acc[o4 * 4 + 3] = fmaf(wv.w, xv, acc[o4 * 4 + 3]);
        }
    }

    float* op = out + (size_t)(b * O + oc0) * NPIX + n;
#pragma unroll
    for (int o = 0; o < OC; ++o) op[(size_t)o * NPIX] = acc[o];
}

// ---------------- pyramid depthwise conv (reflect pad, dilation=group) ------
__device__ __forceinline__ int refl(int p) {
    return (p < 0) ? -p : ((p > 255) ? 510 - p : p);
}

__global__ __launch_bounds__(256) void pyramid_k(const float* __restrict__ in,
                                                 float* __restrict__ out, int C,
                                                 const float* __restrict__ w1,
                                                 const float* __restrict__ w2,
                                                 const float* __restrict__ w3) {
    const int t = threadIdx.x;                 // x coordinate (one block = one row)
    const int bi = blockIdx.x;
    const int y = bi & 255;
    const int bc = bi >> 8;                    // b*C + c
    const int G = C >> 2;
    const int c = bc % C;
    const int g = (c >= 3 * G) ? 3 : (c >= 2 * G) ? 2 : (c >= G) ? 1 : 0;

    const float* src = in + (size_t)bc * NPIX;
    const size_t oidx = (size_t)bi * 256 + t;

    if (g == 0) {
        out[oidx] = src[y * 256 + t];
        return;
    }
    const float* wp = (g == 1 ? w1 : (g == 2 ? w2 : w3)) + (c - g * G) * 9;
    float s = 0.f;
#pragma unroll
    for (int ky = 0; ky < 3; ++ky) {
        const int yy = refl(y + (ky - 1) * g);
        const float* rowp = src + yy * 256;
#pragma unroll
        for (int kx = 0; kx < 3; ++kx) {
            const int xx = refl(t + (kx - 1) * g);
            s = fmaf(wp[ky * 3 + kx], rowp[xx], s);
        }
    }
    out[oidx] = s;
}

// ---------------- fused scores + squared-norm reductions --------------------
// Sbuf layout (floats): [0,1536)  S[b][hd][c(12)][d(16)]  raw q.k dots
//                       [1536,1664) kk[b][hd][d]  sum k^2
//                       [1664,1760) qq[b][hd][c]  sum q^2
__global__ __launch_bounds__(256) void scores_k(const float* __restrict__ qh,
                                                const float* __restrict__ ql,
                                                const float* __restrict__ kv,
                                                float* __restrict__ Sbuf) {
    __shared__ float qs[12 * 513];
    __shared__ float ks[16 * 513];
    const int t = threadIdx.x;
    const int slice = blockIdx.x;  // 0..31
    const int hd = blockIdx.y;     // 0..3
    const int b = blockIdx.z;      // 0..1
    const int n0 = slice * 2048;

    const float* pa = nullptr;
    const float* pb = nullptr;
    if (t < 192) {
        int c = t >> 4, d = t & 15;
        pa = qs + c * 513;
        pb = ks + d * 513;
    } else if (t < 208) {
        int d = t - 192;
        pa = ks + d * 513;
        pb = pa;
    } else if (t < 220) {
        int c = t - 208;
        pa = qs + c * 513;
        pb = pa;
    }

    float acc = 0.f;
    for (int cb = 0; cb < 4; ++cb) {
        const int base = n0 + cb * 512;
        for (int idx = t; idx < 28 * 512; idx += 256) {
            const int row = idx >> 9, i = idx & 511;
            const float* src;
            if (row < 8)
                src = qh + (size_t)(b * 32 + hd * 8 + row) * NPIX;
            else if (row < 12)
                src = ql + (size_t)(b * 16 + hd * 4 + (row - 8)) * NPIX;
            else
                src = kv + (size_t)(b * 128 + hd * 16 + (row - 12)) * NPIX;
            const float v = src[base + i];
            if (row < 12)
                qs[row * 513 + i] = v;
            else
                ks[(row - 12) * 513 + i] = v;
        }
        __syncthreads();
        if (pa) {
#pragma unroll 8
            for (int i = 0; i < 512; ++i) acc = fmaf(pa[i], pb[i], acc);
        }
        __syncthreads();
    }

    if (t < 192) {
        int c = t >> 4, d = t & 15;
        atomicAdd(&Sbuf[((b * 4 + hd) * 12 + c) * 16 + d], acc);
    } else if (t < 208) {
        int d = t - 192;
        atomicAdd(&Sbuf[1536 + (b * 4 + hd) * 16 + d], acc);
    } else if (t < 220) {
        int c = t - 208;
        atomicAdd(&Sbuf[1664 + (b * 4 + hd) * 12 + c], acc);
    }
}

// ---------------- softmax + fold output projections into CT -----------------
// CT[b][j=hd*16+d][r(192)]: rows 0..127 -> out_h channels (w_ph), 128..191 -> out_l.
__global__ __launch_bounds__(256) void finalize_k(const float* __restrict__ Sbuf,
                                                  const float* __restrict__ w_ph,
                                                  const float* __restrict__ w_pl,
                                                  const float* __restrict__ temp,
                                                  float* __restrict__ CT) {
    __shared__ float As[192];
    const int t = threadIdx.x;
    const int hd = blockIdx.x;  // 0..3
    const int b = blockIdx.y;   // 0..1

    if (t < 192) {
        const int c = t >> 4, d = t & 15;
        const float kss = Sbuf[1536 + (b * 4 + hd) * 16 + d];
        const float qss = Sbuf[1664 + (b * 4 + hd) * 12 + c];
        const float invk = 1.f / fmaxf(sqrtf(kss), 1e-12f);
        const float invq = 1.f / fmaxf(sqrtf(qss), 1e-12f);
        float s = Sbuf[((b * 4 + hd) * 12 + c) * 16 + d] * invq * invk * temp[hd];
        float m = s;
        for (int mask = 8; mask >= 1; mask >>= 1) m = fmaxf(m, __shfl_xor(m, mask, 16));
        const float e = expf(s - m);
        float sum = e;
        for (int mask = 8; mask >= 1; mask >>= 1) sum += __shfl_xor(sum, mask, 16);
        As[c * 16 + d] = e / sum;
    }
    __syncthreads();

    for (int idx = t; idx < 3072; idx += 256) {
        const int d = idx & 15, r = idx >> 4;
        float s = 0.f;
        if (r < 128) {
#pragma unroll
            for (int c = 0; c < 8; ++c)
                s = fmaf(w_ph[r * 32 + hd * 8 + c], As[c * 16 + d], s);
        } else {
            const int r2 = r - 128;
#pragma unroll
            for (int c = 0; c < 4; ++c)
                s = fmaf(w_pl[r2 * 16 + hd * 4 + c], As[(8 + c) * 16 + d], s);
        }
        CT[(size_t)(b * 64 + hd * 16 + d) * 192 + r] = s;
    }
}

// ---------------- output GEMM: out rows = CT[b] (192x64) @ v (64xN) ---------
__global__ __launch_bounds__(256) void outgemm_k(const float* __restrict__ vsrc,
                                                 const float* __restrict__ CT,
                                                 float* __restrict__ out) {
    const int t = threadIdx.x;
    const int n = blockIdx.x * 256 + t;
    const int rc = blockIdx.y;  // 0..2 (row chunk of 64)
    const int b = blockIdx.z;

    const float* vp = vsrc + (size_t)(b * 128 + 64) * NPIX + n;
    const float* ct = CT + (size_t)b * 64 * 192 + rc * 64;

    float acc[64];
#pragma unroll
    for (int r = 0; r < 64; ++r) acc[r] = 0.f;

    for (int j = 0; j < 64; ++j) {
        const float xv = vp[(size_t)j * NPIX];
        const float4* cr = (const float4*)(ct + j * 192);
#pragma unroll
        for (int o4 = 0; o4 < 16; ++o4) {
            float4 wv = cr[o4];
            acc[o4 * 4 + 0] = fmaf(wv.x, xv, acc[o4 * 4 + 0]);
            acc[o4 * 4 + 1] = fmaf(wv.y, xv, acc[o4 * 4 + 1]);
            acc[o4 * 4 + 2] = fmaf(wv.z, xv, acc[o4 * 4 + 2]);
            acc[o4 * 4 + 3] = fmaf(wv.w, xv, acc[o4 * 4 + 3]);
        }
    }

    if (rc < 2) {
        float* op = out + (size_t)(b * 128 + rc * 64) * NPIX + n;
#pragma unroll
        for (int r = 0; r < 64; ++r) op[(size_t)r * NPIX] = acc[r];
    } else {
        float* op = out + (size_t)2 * 128 * NPIX + (size_t)(b * 64) * NPIX + n;
#pragma unroll
        for (int r = 0; r < 64; ++r) op[(size_t)r * NPIX] = acc[r];
    }
}

// ---------------------------------------------------------------------------
extern "C" void kernel_launch(void* const* d_in, const int* in_sizes, int n_in,
                              void* d_out, int out_size, void* d_ws, size_t ws_size,
                              hipStream_t stream) {
    const float* x      = (const float*)d_in[0];
    const float* x_h    = (const float*)d_in[1];
    const float* x_l    = (const float*)d_in[2];
    const float* w_kv   = (const float*)d_in[3];
    const float* kv_dw1 = (const float*)d_in[4];
    const float* kv_dw2 = (const float*)d_in[5];
    const float* kv_dw3 = (const float*)d_in[6];
    const float* w_qh   = (const float*)d_in[7];
    const float* qh_dw1 = (const float*)d_in[8];
    const float* qh_dw2 = (const float*)d_in[9];
    const float* qh_dw3 = (const float*)d_in[10];
    const float* w_ql   = (const float*)d_in[11];
    const float* ql_dw1 = (const float*)d_in[12];
    const float* ql_dw2 = (const float*)d_in[13];
    const float* ql_dw3 = (const float*)d_in[14];
    const float* w_ph   = (const float*)d_in[15];
    const float* w_pl   = (const float*)d_in[16];
    const float* temp   = (const float*)d_in[17];
    float* out = (float*)d_out;

    char* ws = (char*)d_ws;
    // workspace layout (bytes)
    float* Sbuf  = (float*)(ws + 0);            // 7040 B used
    float* wkvT  = (float*)(ws + 8192);         // 131072 B
    float* wqhT  = (float*)(ws + 139264);       // 16384 B
    float* wqlT  = (float*)(ws + 155648);       // 4096 B
    float* CT    = (float*)(ws + 159744);       // 98304 B
    float* kvraw = (float*)(ws + 262144);       // 67108864 B
    float* kvpyr = (float*)(ws + 262144 + 67108864);
    float* qhraw = (float*)(ws + 262144 + 2 * 67108864);
    float* qhpyr = (float*)(ws + 262144 + 2 * 67108864 + 16777216);
    float* qlraw = (float*)(ws + 262144 + 2 * 67108864 + 2 * 16777216);
    float* qlpyr = (float*)(ws + 262144 + 2 * 67108864 + 2 * 16777216 + 8388608);

    zero_k<<<7, 256, 0, stream>>>(Sbuf, 1760);
    transpose_w_k<<<148, 256, 0, stream>>>(w_kv, w_qh, w_ql, wkvT, wqhT, wqlT);

    conv1x1_k<64><<<dim3(256, 2, 2), 256, 0, stream>>>(x,   wkvT, kvraw, 256, 128);
    conv1x1_k<32><<<dim3(256, 1, 2), 256, 0, stream>>>(x_h, wqhT, qhraw, 128, 32);
    conv1x1_k<16><<<dim3(256, 1, 2), 256, 0, stream>>>(x_l, wqlT, qlraw, 64, 16);

    pyramid_k<<<65536, 256, 0, stream>>>(kvraw, kvpyr, 128, kv_dw1, kv_dw2, kv_dw3);
    pyramid_k<<<16384, 256, 0, stream>>>(qhraw, qhpyr, 32, qh_dw1, qh_dw2, qh_dw3);
    pyramid_k<<<8192, 256, 0, stream>>>(qlraw, qlpyr, 16, ql_dw1, ql_dw2, ql_dw3);

    scores_k<<<dim3(32, 4, 2), 256, 0, stream>>>(qhpyr, qlpyr, kvpyr, Sbuf);
    finalize_k<<<dim3(4, 2), 256, 0, stream>>>(Sbuf, w_ph, w_pl, temp, CT);
    outgemm_k<<<dim3(256, 3, 2), 256, 0, stream>>>(kvpyr, CT, out);
}

// Round 2
// 471.029 us; speedup vs baseline: 1.2125x; 1.2125x over previous
//
#include <hip/hip_runtime.h>
#include <hip/hip_bf16.h>

// ---------------------------------------------------------------------------
// CrossLevelAttention on MI355X — round 2: bf16 MFMA for all GEMM-shaped ops.
// B=2, H=W=256, N=65536. dim=256, dim_h=128, dim_l=64, HEADS=4.
//   1x1 convs (kv/qh/ql) via mfma_f32_16x16x32_bf16 (A=weights direct from
//   global, B=activations staged transposed in LDS, fp32 out)
//   -> pyramid dwconv (fp32) -> fused scores+sq-norms (fp32)
//   -> softmax+projection-fold (CT, bf16) -> output GEMM via MFMA.
// ---------------------------------------------------------------------------

#define NPIX 65536  // 256*256 per batch image

using bf16x8 = __attribute__((ext_vector_type(8))) short;
using f32x4  = __attribute__((ext_vector_type(4))) float;

__device__ __forceinline__ unsigned short f2bf(float f) {
    unsigned u = __builtin_bit_cast(unsigned, f);
    u = u + 0x7FFF + ((u >> 16) & 1);   // RNE
    return (unsigned short)(u >> 16);
}

// ---------------- zero small accumulator region ----------------
__global__ void zero_k(float* __restrict__ p, int n) {
    int i = blockIdx.x * 256 + threadIdx.x;
    if (i < n) p[i] = 0.f;
}

// ---------------- cast 1x1 weights to bf16 (keep [o][k] layout) -------------
__global__ void cast_w_k(const float* __restrict__ w_kv,
                         const float* __restrict__ w_qh,
                         const float* __restrict__ w_ql,
                         unsigned short* __restrict__ wkv_b,
                         unsigned short* __restrict__ wqh_b,
                         unsigned short* __restrict__ wql_b) {
    int idx = blockIdx.x * 256 + threadIdx.x;
    if (idx < 32768) wkv_b[idx] = f2bf(w_kv[idx]);
    else if (idx < 32768 + 4096) wqh_b[idx - 32768] = f2bf(w_qh[idx - 32768]);
    else if (idx < 32768 + 4096 + 1024) wql_b[idx - 36864] = f2bf(w_ql[idx - 36864]);
}

// ---------------- generic MFMA GEMM over pixel dimension --------------------
// out[b][o][n] = sum_k A[o][k] * src[b][k][n],  O = MW*MSPLIT*16, K = KT*32.
// One 64-pixel chunk per iteration; B staged transposed+bf16-packed in LDS.
template <int MW, int MSPLIT, int KT, int CPB, bool SPLIT>
__global__ __launch_bounds__(256) void gemm_mfma_k(
    const float* __restrict__ src, const unsigned short* __restrict__ A,
    float* __restrict__ out, float* __restrict__ out2,
    long srcBStride, long aBStride, long outBStride, long out2BStride) {
    constexpr int K  = KT * 32;
    constexpr int RW = K / 2 + 4;   // LDS row pitch in 32-bit words (16B-aligned)
    constexpr int NW = MSPLIT;      // N tiles per wave (chunk is always 64 px)

    __shared__ unsigned Blds[64 * RW];

    const int t    = threadIdx.x;
    const int wave = t >> 6;
    const int lane = t & 63;
    const int r    = lane & 15;
    const int q    = lane >> 4;

    const int chunk0 = blockIdx.x * CPB;
    const int b      = chunk0 >> 10;          // 1024 chunks per batch
    const int m0     = (wave % MSPLIT) * MW * 16;
    const int nb     = (wave / MSPLIT) * NW * 16;

    // A fragments: [o][k] bf16, k-contiguous -> direct 16B loads
    bf16x8 af[MW][KT];
    {
        const unsigned short* Ab = A + (size_t)b * aBStride;
#pragma unroll
        for (int mw = 0; mw < MW; ++mw)
#pragma unroll
            for (int kt = 0; kt < KT; ++kt)
                af[mw][kt] = *(const bf16x8*)(Ab + (size_t)(m0 + mw * 16 + r) * K + kt * 32 + q * 8);
    }

    const float* srcb = src + (size_t)b * srcBStride;

    for (int cc = 0; cc < CPB; ++cc) {
        const int chunk = chunk0 + cc;
        const int n0 = (chunk & 1023) * 64;

        // stage K x 64 fp32 -> LDS bf16 transposed [n][k/2 packed]
        {
            const int sn = t & 63, kp0 = t >> 6;
            const float* sp = srcb + n0 + sn;
#pragma unroll
            for (int it = 0; it < K / 8; ++it) {
                const int kp = it * 4 + kp0;
                const float v0 = sp[(size_t)(2 * kp) * NPIX];
                const float v1 = sp[(size_t)(2 * kp + 1) * NPIX];
                Blds[sn * RW + kp] = (unsigned)f2bf(v0) | ((unsigned)f2bf(v1) << 16);
            }
        }
        __syncthreads();

        f32x4 acc[MW][NW];
#pragma unroll
        for (int mw = 0; mw < MW; ++mw)
#pragma unroll
            for (int nw = 0; nw < NW; ++nw) acc[mw][nw] = (f32x4){0.f, 0.f, 0.f, 0.f};

#pragma unroll
        for (int kt = 0; kt < KT; ++kt) {
            bf16x8 bf[NW];
#pragma unroll
            for (int nw = 0; nw < NW; ++nw) {
                const int n = nb + nw * 16 + r;
                bf[nw] = *(const bf16x8*)(&Blds[n * RW + kt * 16 + q * 4]);
            }
#pragma unroll
            for (int mw = 0; mw < MW; ++mw)
#pragma unroll
                for (int nw = 0; nw < NW; ++nw)
                    acc[mw][nw] = __builtin_amdgcn_mfma_f32_16x16x32_bf16(
                        af[mw][kt], bf[nw], acc[mw][nw], 0, 0, 0);
        }

        // store: C/D layout col=lane&15 (pixel), row=(lane>>4)*4+reg (channel)
#pragma unroll
        for (int mw = 0; mw < MW; ++mw) {
            const int obase = m0 + mw * 16 + q * 4;
#pragma unroll
            for (int nw = 0; nw < NW; ++nw) {
                const int n = n0 + nb + nw * 16 + r;
#pragma unroll
                for (int rr = 0; rr < 4; ++rr) {
                    const int o = obase + rr;
                    float* dst;
                    if (SPLIT && o >= 128)
                        dst = out2 + (size_t)b * out2BStride + (size_t)(o - 128) * NPIX + n;
                    else
                        dst = out + (size_t)b * outBStride + (size_t)o * NPIX + n;
                    *dst = acc[mw][nw][rr];
                }
            }
        }
        __syncthreads();
    }
}

// ---------------- pyramid depthwise conv (reflect pad, dilation=group) ------
__device__ __forceinline__ int refl(int p) {
    return (p < 0) ? -p : ((p > 255) ? 510 - p : p);
}

__global__ __launch_bounds__(256) void pyramid_k(const float* __restrict__ in,
                                                 float* __restrict__ out, int C,
                                                 const float* __restrict__ w1,
                                                 const float* __restrict__ w2,
                                                 const float* __restrict__ w3) {
    const int t = threadIdx.x;
    const int bi = blockIdx.x;
    const int y = bi & 255;
    const int bc = bi >> 8;
    const int G = C >> 2;
    const int c = bc % C;
    const int g = (c >= 3 * G) ? 3 : (c >= 2 * G) ? 2 : (c >= G) ? 1 : 0;

    const float* src = in + (size_t)bc * NPIX;
    const size_t oidx = (size_t)bi * 256 + t;

    if (g == 0) {
        out[oidx] = src[y * 256 + t];
        return;
    }
    const float* wp = (g == 1 ? w1 : (g == 2 ? w2 : w3)) + (c - g * G) * 9;
    float s = 0.f;
#pragma unroll
    for (int ky = 0; ky < 3; ++ky) {
        const int yy = refl(y + (ky - 1) * g);
        const float* rowp = src + yy * 256;
#pragma unroll
        for (int kx = 0; kx < 3; ++kx) {
            const int xx = refl(t + (kx - 1) * g);
            s = fmaf(wp[ky * 3 + kx], rowp[xx], s);
        }
    }
    out[oidx] = s;
}

// ---------------- fused scores + squared-norm reductions --------------------
// Sbuf layout (floats): [0,1536)  S[b][hd][c(12)][d(16)]  raw q.k dots
//                       [1536,1664) kk[b][hd][d]  sum k^2
//                       [1664,1760) qq[b][hd][c]  sum q^2
__global__ __launch_bounds__(256) void scores_k(const float* __restrict__ qh,
                                                const float* __restrict__ ql,
                                                const float* __restrict__ kv,
                                                float* __restrict__ Sbuf) {
    __shared__ float qs[12 * 513];
    __shared__ float ks[16 * 513];
    const int t = threadIdx.x;
    const int slice = blockIdx.x;
    const int hd = blockIdx.y;
    const int b = blockIdx.z;
    const int n0 = slice * 2048;

    const float* pa = nullptr;
    const float* pb = nullptr;
    if (t < 192) {
        int c = t >> 4, d = t & 15;
        pa = qs + c * 513;
        pb = ks + d * 513;
    } else if (t < 208) {
        int d = t - 192;
        pa = ks + d * 513;
        pb = pa;
    } else if (t < 220) {
        int c = t - 208;
        pa = qs + c * 513;
        pb = pa;
    }

    float acc = 0.f;
    for (int cb = 0; cb < 4; ++cb) {
        const int base = n0 + cb * 512;
        for (int idx = t; idx < 28 * 512; idx += 256) {
            const int row = idx >> 9, i = idx & 511;
            const float* src;
            if (row < 8)
                src = qh + (size_t)(b * 32 + hd * 8 + row) * NPIX;
            else if (row < 12)
                src = ql + (size_t)(b * 16 + hd * 4 + (row - 8)) * NPIX;
            else
                src = kv + (size_t)(b * 128 + hd * 16 + (row - 12)) * NPIX;
            const float v = src[base + i];
            if (row < 12)
                qs[row * 513 + i] = v;
            else
                ks[(row - 12) * 513 + i] = v;
        }
        __syncthreads();
        if (pa) {
#pragma unroll 8
            for (int i = 0; i < 512; ++i) acc = fmaf(pa[i], pb[i], acc);
        }
        __syncthreads();
    }

    if (t < 192) {
        int c = t >> 4, d = t & 15;
        atomicAdd(&Sbuf[((b * 4 + hd) * 12 + c) * 16 + d], acc);
    } else if (t < 208) {
        int d = t - 192;
        atomicAdd(&Sbuf[1536 + (b * 4 + hd) * 16 + d], acc);
    } else if (t < 220) {
        int c = t - 208;
        atomicAdd(&Sbuf[1664 + (b * 4 + hd) * 12 + c], acc);
    }
}

// ---------------- softmax + fold output projections into CT (bf16) ---------
// CT[b][r(192)][j=hd*16+d (64)]: rows 0..127 -> out_h (w_ph), 128..191 -> out_l.
__global__ __launch_bounds__(256) void finalize_k(const float* __restrict__ Sbuf,
                                                  const float* __restrict__ w_ph,
                                                  const float* __restrict__ w_pl,
                                                  const float* __restrict__ temp,
                                                  unsigned short* __restrict__ CT) {
    __shared__ float As[192];
    const int t = threadIdx.x;
    const int hd = blockIdx.x;
    const int b = blockIdx.y;

    if (t < 192) {
        const int c = t >> 4, d = t & 15;
        const float kss = Sbuf[1536 + (b * 4 + hd) * 16 + d];
        const float qss = Sbuf[1664 + (b * 4 + hd) * 12 + c];
        const float invk = 1.f / fmaxf(sqrtf(kss), 1e-12f);
        const float invq = 1.f / fmaxf(sqrtf(qss), 1e-12f);
        float s = Sbuf[((b * 4 + hd) * 12 + c) * 16 + d] * invq * invk * temp[hd];
        float m = s;
        for (int mask = 8; mask >= 1; mask >>= 1) m = fmaxf(m, __shfl_xor(m, mask, 16));
        const float e = expf(s - m);
        float sum = e;
        for (int mask = 8; mask >= 1; mask >>= 1) sum += __shfl_xor(sum, mask, 16);
        As[c * 16 + d] = e / sum;
    }
    __syncthreads();

    unsigned short* CTb = CT + (size_t)b * 192 * 64;
    for (int idx = t; idx < 3072; idx += 256) {
        const int d = idx & 15, rr = idx >> 4;
        float s = 0.f;
        if (rr < 128) {
#pragma unroll
            for (int c = 0; c < 8; ++c)
                s = fmaf(w_ph[rr * 32 + hd * 8 + c], As[c * 16 + d], s);
        } else {
            const int r2 = rr - 128;
#pragma unroll
            for (int c = 0; c < 4; ++c)
                s = fmaf(w_pl[r2 * 16 + hd * 4 + c], As[(8 + c) * 16 + d], s);
        }
        CTb[(size_t)rr * 64 + hd * 16 + d] = f2bf(s);
    }
}

// ---------------------------------------------------------------------------
extern "C" void kernel_launch(void* const* d_in, const int* in_sizes, int n_in,
                              void* d_out, int out_size, void* d_ws, size_t ws_size,
                              hipStream_t stream) {
    const float* x      = (const float*)d_in[0];
    const float* x_h    = (const float*)d_in[1];
    const float* x_l    = (const float*)d_in[2];
    const float* w_kv   = (const float*)d_in[3];
    const float* kv_dw1 = (const float*)d_in[4];
    const float* kv_dw2 = (const float*)d_in[5];
    const float* kv_dw3 = (const float*)d_in[6];
    const float* w_qh   = (const float*)d_in[7];
    const float* qh_dw1 = (const float*)d_in[8];
    const float* qh_dw2 = (const float*)d_in[9];
    const float* qh_dw3 = (const float*)d_in[10];
    const float* w_ql   = (const float*)d_in[11];
    const float* ql_dw1 = (const float*)d_in[12];
    const float* ql_dw2 = (const float*)d_in[13];
    const float* ql_dw3 = (const float*)d_in[14];
    const float* w_ph   = (const float*)d_in[15];
    const float* w_pl   = (const float*)d_in[16];
    const float* temp   = (const float*)d_in[17];
    float* out = (float*)d_out;

    char* ws = (char*)d_ws;
    float*          Sbuf  = (float*)(ws + 0);        // 7040 B
    unsigned short* wkv_b = (unsigned short*)(ws + 8192);    // 65536 B
    unsigned short* wqh_b = (unsigned short*)(ws + 73728);   // 8192 B
    unsigned short* wql_b = (unsigned short*)(ws + 81920);   // 2048 B
    unsigned short* CT    = (unsigned short*)(ws + 90112);   // 49152 B
    float* kvraw = (float*)(ws + 262144);
    float* kvpyr = (float*)(ws + 262144 + 67108864);
    float* qhraw = (float*)(ws + 262144 + 2 * 67108864);
    float* qhpyr = (float*)(ws + 262144 + 2 * 67108864 + 16777216);
    float* qlraw = (float*)(ws + 262144 + 2 * 67108864 + 2 * 16777216);
    float* qlpyr = (float*)(ws + 262144 + 2 * 67108864 + 2 * 16777216 + 8388608);

    zero_k<<<7, 256, 0, stream>>>(Sbuf, 1760);
    cast_w_k<<<148, 256, 0, stream>>>(w_kv, w_qh, w_ql, wkv_b, wqh_b, wql_b);

    // kv: O=128 (MW=4,MS=2), K=256 (KT=8)
    gemm_mfma_k<4, 2, 8, 4, false><<<512, 256, 0, stream>>>(
        x, wkv_b, kvraw, nullptr, 256L * NPIX, 0L, 128L * NPIX, 0L);
    // qh: O=32 (MW=2,MS=1), K=128 (KT=4)
    gemm_mfma_k<2, 1, 4, 4, false><<<512, 256, 0, stream>>>(
        x_h, wqh_b, qhraw, nullptr, 128L * NPIX, 0L, 32L * NPIX, 0L);
    // ql: O=16 (MW=1,MS=1), K=64 (KT=2)
    gemm_mfma_k<1, 1, 2, 4, false><<<512, 256, 0, stream>>>(
        x_l, wql_b, qlraw, nullptr, 64L * NPIX, 0L, 16L * NPIX, 0L);

    pyramid_k<<<65536, 256, 0, stream>>>(kvraw, kvpyr, 128, kv_dw1, kv_dw2, kv_dw3);
    pyramid_k<<<16384, 256, 0, stream>>>(qhraw, qhpyr, 32, qh_dw1, qh_dw2, qh_dw3);
    pyramid_k<<<8192, 256, 0, stream>>>(qlraw, qlpyr, 16, ql_dw1, ql_dw2, ql_dw3);

    scores_k<<<dim3(32, 4, 2), 256, 0, stream>>>(qhpyr, qlpyr, kvpyr, Sbuf);
    finalize_k<<<dim3(4, 2), 256, 0, stream>>>(Sbuf, w_ph, w_pl, temp, CT);

    // output GEMM: O=192 (MW=6,MS=2), K=64 (KT=2); A = CT per batch;
    // B = v (second half of kvpyr); rows >=128 go to out_l.
    gemm_mfma_k<6, 2, 2, 4, true><<<512, 256, 0, stream>>>(
        kvpyr + 64L * NPIX, CT, out, out + 2L * 128 * NPIX,
        128L * NPIX, 192L * 64, 128L * NPIX, 64L * NPIX);
}